// Round 1
// baseline (154.732 us; speedup 1.0000x reference)
//
#include <hip/hip_runtime.h>
#include <hip/hip_bf16.h>
#include <cstdint>
#include <math.h>

// Shapes: B=256, P=128, K=512, HE=1024, HF=512 (2HF=1024), D=2560, HID=64
// Outputs: embeddings (256,1,1536) then weights (256,128), fp32, flat-concat.
//
// R8: occupancy-first restructure.
//   prep: w1kt repack (16 blocks) + fp32 proj GEMV (64 blocks x 4 batches)
//         -> proj[256][64]. w1qft eliminated (was 64 MB/iter of L2 re-reads).
//   attn: 512 threads/block (8 waves x 16 rows -> 2 waves/SIMD, was 1).
//         MFMA A-fragments load DIRECT from global (2x float4/lane/kk,
//         128 B per row per kk), cvt->bf16, ds_write into sk for the
//         context phase. No separate staging phase; loads hide under MFMA
//         + 6 outstanding wave-loads, x2 waves/SIMD.
// Ledger (attn-path µs): R2 fused 39 | R3 split 44 | R5 interleave 95 |
//   R6 handshake 65 | R7 fused+dbuf 36-42 (1 wave/SIMD, latency-bound,
//   VGPR=68 proves the 16-deep reg pipeline was never materialized).
// Fixed harness overhead: ~82 µs of 256 MiB workspace-poison fills per
//   iteration (2 x 41 µs fillBufferAligned) — not addressable from here.

typedef __bf16 bf16;
typedef __attribute__((ext_vector_type(8))) __bf16 bf16x8;
typedef __attribute__((ext_vector_type(4))) float f32x4;

#define NB 256
#define NP 128
#define NK 512
#define SKLD 520   // keys LDS row stride (bf16): 1040B/row -> 2-way bank alias (free)
#define SK_BYTES (NP * SKLD * 2)                      // 133120
#define SMEM_BYTES (SK_BYTES + 128 * 4 + 128 * 4)    // + scores[128] + wts[128]

// ---------------- prep: w1kt repack + fp32 proj ----------------
// blocks 0..15 : w1kt[h][k] = bf16(W1[k*64+h]), k-rows [32j,32j+32)
// blocks 16..79: proj[b][h] = sum_d qf[b][d]*W1[512+d][h], 4 batches/block
__global__ __launch_bounds__(256) void prep_kernel(
    const float* __restrict__ W1, const float* __restrict__ query,
    const float* __restrict__ frame, bf16* __restrict__ w1kt,
    float* __restrict__ proj)
{
    const int blk = blockIdx.x;
    const int t = threadIdx.x;
    if (blk < 16) {
        __shared__ float s[32][65];
        const int k0 = blk * 32;
#pragma unroll
        for (int i = 0; i < 8; i++) {
            const int idx = t + 256 * i;
            const int k = idx >> 6, h = idx & 63;
            s[k][h] = W1[(size_t)(k0 + k) * 64 + h];
        }
        __syncthreads();
#pragma unroll
        for (int i = 0; i < 8; i++) {
            const int idx = t + 256 * i;
            const int h = idx >> 5, kk = idx & 31;
            w1kt[(size_t)h * 512 + k0 + kk] = (bf16)s[kk][h];
        }
    } else {
        __shared__ float red[4][4][64];
        const int b0 = (blk - 16) * 4;
        const int c = t >> 6;      // d-chunk (wave-uniform)
        const int h = t & 63;
        // qf = concat(query[1024], frame[1024]); chunk c covers d in [512c,512c+512)
        const float* q0 = (c < 2) ? (query + c * 512) : (frame + (c - 2) * 512);
        const float* w1r = W1 + (size_t)(512 + c * 512) * 64 + h;  // coalesced over h
        float a0[4] = {0.f, 0.f, 0.f, 0.f};
        float a1[4] = {0.f, 0.f, 0.f, 0.f};
#pragma unroll 4
        for (int d = 0; d < 512; d += 2) {
            const float w0  = w1r[(size_t)d * 64];
            const float w1v = w1r[(size_t)(d + 1) * 64];
#pragma unroll
            for (int j = 0; j < 4; j++) {
                a0[j] += q0[(size_t)(b0 + j) * 1024 + d] * w0;
                a1[j] += q0[(size_t)(b0 + j) * 1024 + d + 1] * w1v;
            }
        }
#pragma unroll
        for (int j = 0; j < 4; j++) red[c][j][h] = a0[j] + a1[j];
        __syncthreads();
        const int j2 = t >> 6;
        proj[(size_t)(b0 + j2) * 64 + h] =
            red[0][j2][h] + red[1][j2][h] + red[2][j2][h] + red[3][j2][h];
    }
}

// ---------------- attn: one 512-thread block per batch ----------------
__global__ __launch_bounds__(512) void attn_kernel(
    const float* __restrict__ keys, const float* __restrict__ frame,
    const int* __restrict__ mask, const float* __restrict__ W2,
    const bf16* __restrict__ w1kt, const float* __restrict__ proj,
    float* __restrict__ out)
{
    extern __shared__ char smem[];
    bf16* sk      = (bf16*)smem;                  // [128][520] bf16
    float* scores = (float*)(smem + SK_BYTES);    // [128]
    float* wts    = scores + 128;                 // [128]

    const int b = blockIdx.x;
    const int t = threadIdx.x;
    const int w = t >> 6;          // wave id 0..7
    const int lane = t & 63;
    const int m = lane & 15;
    const int q = lane >> 4;
    const int p0 = w * 16;         // this wave's 16 key rows

    // per-lane fold constants (L2-hot, issued early, consumed after kk loop)
    float pv[4], wv[4];
#pragma unroll
    for (int nt = 0; nt < 4; nt++) {
        pv[nt] = proj[b * 64 + nt * 16 + m];
        wv[nt] = W2[nt * 16 + m];
    }

    // ---- scores: C[p][h] = relu(keys@W1k + proj) @ W2, A direct-from-global ----
    const float* arow = keys + (size_t)b * (NP * NK) + (size_t)(p0 + m) * NK + q * 8;
    const bf16* bb = w1kt + m * 512 + q * 8;                  // + nt*8192 + kk*32
    bf16* swr = sk + (size_t)(p0 + m) * SKLD + q * 8;         // LDS stage for context

    f32x4 acc[4];
#pragma unroll
    for (int nt = 0; nt < 4; nt++) acc[nt] = (f32x4){0.f, 0.f, 0.f, 0.f};

    float4 Aa[2], Ab[2];
    bf16x8 Bp[2][4];
    Aa[0] = *(const float4*)(arow);
    Ab[0] = *(const float4*)(arow + 4);
#pragma unroll
    for (int nt = 0; nt < 4; nt++) Bp[0][nt] = *(const bf16x8*)(bb + nt * 8192);

#pragma unroll
    for (int kk = 0; kk < 16; kk++) {
        const int cur = kk & 1;
        if (kk < 15) {
            Aa[cur ^ 1] = *(const float4*)(arow + (kk + 1) * 32);
            Ab[cur ^ 1] = *(const float4*)(arow + (kk + 1) * 32 + 4);
#pragma unroll
            for (int nt = 0; nt < 4; nt++)
                Bp[cur ^ 1][nt] = *(const bf16x8*)(bb + nt * 8192 + (kk + 1) * 32);
        }
        bf16x8 Af;
        Af[0] = (bf16)Aa[cur].x; Af[1] = (bf16)Aa[cur].y;
        Af[2] = (bf16)Aa[cur].z; Af[3] = (bf16)Aa[cur].w;
        Af[4] = (bf16)Ab[cur].x; Af[5] = (bf16)Ab[cur].y;
        Af[6] = (bf16)Ab[cur].z; Af[7] = (bf16)Ab[cur].w;
        *(bf16x8*)(swr + kk * 32) = Af;     // stage bf16 keys for context phase
#pragma unroll
        for (int nt = 0; nt < 4; nt++)
            acc[nt] = __builtin_amdgcn_mfma_f32_16x16x32_bf16(Af, Bp[cur][nt], acc[nt], 0, 0, 0);
    }

    // fold 64 h-columns: relu(+proj) * w2, then reduce over the 16 h-lanes
    float pr[4] = {0.f, 0.f, 0.f, 0.f};
#pragma unroll
    for (int nt = 0; nt < 4; nt++)
#pragma unroll
        for (int r = 0; r < 4; r++)
            pr[r] += fmaxf(acc[nt][r] + pv[nt], 0.f) * wv[nt];

#pragma unroll
    for (int off = 1; off < 16; off <<= 1)
#pragma unroll
        for (int r = 0; r < 4; r++)
            pr[r] += __shfl_xor(pr[r], off);

    if (m == 0) {
#pragma unroll
        for (int r = 0; r < 4; r++) scores[p0 + q * 4 + r] = pr[r];
    }
    __syncthreads();

    // ---- masked softmax over 128 scores (wave 0), write weights ----
    if (t < 64) {
        const int pa = t, pb = t + 64;
        float s0 = (mask[b * 128 + pa] == 0) ? -INFINITY : scores[pa];
        float s1 = (mask[b * 128 + pb] == 0) ? -INFINITY : scores[pb];
        float mx = fmaxf(s0, s1);
#pragma unroll
        for (int off = 32; off; off >>= 1) mx = fmaxf(mx, __shfl_xor(mx, off));
        float e0 = __expf(s0 - mx), e1 = __expf(s1 - mx);
        float sum = e0 + e1;
#pragma unroll
        for (int off = 32; off; off >>= 1) sum += __shfl_xor(sum, off);
        const float inv = 1.0f / sum;
        e0 *= inv; e1 *= inv;
        wts[pa] = e0; wts[pb] = e1;
        float* wout = out + (size_t)NB * 1536;
        wout[b * 128 + pa] = e0;
        wout[b * 128 + pb] = e1;
    }
    __syncthreads();

    // ---- context[k] = sum_p w[p]*keys_bf16[p][k]; thread owns col t ----
    {
        float c0 = 0.f, c1 = 0.f;
#pragma unroll 8
        for (int p = 0; p < 128; p += 2) {
            const uint32_t u0 = (uint32_t)*(const uint16_t*)(sk + (size_t)p * SKLD + t);
            const uint32_t u1 = (uint32_t)*(const uint16_t*)(sk + (size_t)(p + 1) * SKLD + t);
            c0 += wts[p] * __uint_as_float(u0 << 16);
            c1 += wts[p + 1] * __uint_as_float(u1 << 16);
        }
        out[(size_t)b * 1536 + t] = c0 + c1;
    }
    // ---- frame passthrough: embeddings[:, 512:1536] = frameLSTM_h ----
    if (t < 256) {
        const float4 fv = *(const float4*)(frame + (size_t)b * 1024 + t * 4);
        *(float4*)(out + (size_t)b * 1536 + 512 + t * 4) = fv;
    }
}

extern "C" void kernel_launch(void* const* d_in, const int* in_sizes, int n_in,
                              void* d_out, int out_size, void* d_ws, size_t ws_size,
                              hipStream_t stream) {
    const float* query = (const float*)d_in[0];
    const float* keys  = (const float*)d_in[1];
    const float* frame = (const float*)d_in[2];
    const int*   mask  = (const int*)d_in[3];
    const float* W1    = (const float*)d_in[4];
    const float* W2    = (const float*)d_in[5];
    float* out = (float*)d_out;

    // ws: [0,64K) w1kt bf16 [64][512]; [64K,128K) proj fp32 [256][64]
    bf16* w1kt  = (bf16*)d_ws;
    float* proj = (float*)((char*)d_ws + (64 << 10));

    hipFuncSetAttribute((const void*)attn_kernel,
                        hipFuncAttributeMaxDynamicSharedMemorySize, SMEM_BYTES);

    prep_kernel<<<80, 256, 0, stream>>>(W1, query, frame, w1kt, proj);
    attn_kernel<<<256, 512, SMEM_BYTES, stream>>>(keys, frame, mask, W2,
                                                  w1kt, proj, out);
}

// Round 2
// 136.798 us; speedup vs baseline: 1.1311x; 1.1311x over previous
//
#include <hip/hip_runtime.h>
#include <hip/hip_bf16.h>
#include <cstdint>
#include <math.h>

// Shapes: B=256, P=128, K=512, HE=1024, HF=512 (2HF=1024), D=2560, HID=64
// Outputs: embeddings (256,1,1536) then weights (256,128), fp32, flat-concat.
//
// R9: fix prep GEMV latency. R8's GEMV issued 2560 wave-uniform scalar q-loads
//     per wave (serialized at HBM/L2 latency -> ~25-30 us, the R8 regression).
//     Now: qf staged to LDS once (coalesced float4), d-loop reads only W1
//     (coalesced 256 B/wave/step) with explicit 16-wide double-buffered
//     register prefetch. Per-block: 512 KB W1 from L2 ~= 3.6 us wall.
//     attn kept from R8 (keys-HBM-bound, floor ~10.4 us: 256 KB/block at
//     24.6 GB/s per-CU HBM share).
// Ledger (attn-path µs): R2 fused 39 | R3 split 44 | R5 interleave 95 |
//   R6 handshake 65 | R7 fused+dbuf 36-42 (1 wave/SIMD) | R8 direct-global
//   MFMA-A, 2 waves/SIMD, <41 (not in top-5; prep regressed instead).
// Fixed harness overhead: ~82 µs of 256 MiB workspace-poison fills per
//   iteration (2 x 41 µs fillBufferAligned) — not addressable from here.

typedef __bf16 bf16;
typedef __attribute__((ext_vector_type(8))) __bf16 bf16x8;
typedef __attribute__((ext_vector_type(4))) float f32x4;

#define NB 256
#define NP 128
#define NK 512
#define SKLD 520   // keys LDS row stride (bf16): 1040B/row -> 2-way bank alias (free)
#define SK_BYTES (NP * SKLD * 2)                      // 133120
#define SMEM_BYTES (SK_BYTES + 128 * 4 + 128 * 4)    // + scores[128] + wts[128]

// ---------------- prep: w1kt repack + fp32 proj ----------------
// blocks 0..15 : w1kt[h][k] = bf16(W1[k*64+h]), k-rows [32j,32j+32)
// blocks 16..79: proj[b][h] = sum_d qf[b][d]*W1[512+d][h], 4 batches/block
__global__ __launch_bounds__(256) void prep_kernel(
    const float* __restrict__ W1, const float* __restrict__ query,
    const float* __restrict__ frame, bf16* __restrict__ w1kt,
    float* __restrict__ proj)
{
    const int blk = blockIdx.x;
    const int t = threadIdx.x;
    if (blk < 16) {
        __shared__ float s[32][65];
        const int k0 = blk * 32;
#pragma unroll
        for (int i = 0; i < 8; i++) {
            const int idx = t + 256 * i;
            const int k = idx >> 6, h = idx & 63;
            s[k][h] = W1[(size_t)(k0 + k) * 64 + h];
        }
        __syncthreads();
#pragma unroll
        for (int i = 0; i < 8; i++) {
            const int idx = t + 256 * i;
            const int h = idx >> 5, kk = idx & 31;
            w1kt[(size_t)h * 512 + k0 + kk] = (bf16)s[kk][h];
        }
    } else {
        // ---- proj GEMV: 4 batches/block, q staged in LDS, W1 prefetched ----
        __shared__ float sq[4][2048];        // 32 KB: qf for 4 batches
        __shared__ float red[4][4][64];      // 4 KB: cross-wave reduce
        const int b0 = (blk - 16) * 4;

        // stage qf = concat(query[b], frame[b]) coalesced: 8 float4 / thread
#pragma unroll
        for (int i = 0; i < 8; i++) {
            const int flat = (t + 256 * i) * 4;   // float index 0..8191
            const int bl = flat >> 11;            // local batch 0..3
            const int d  = flat & 2047;
            const float* src = (d < 1024)
                ? (query + (size_t)(b0 + bl) * 1024 + d)
                : (frame + (size_t)(b0 + bl) * 1024 + (d - 1024));
            *(float4*)&sq[bl][d] = *(const float4*)src;
        }
        __syncthreads();

        const int c = t >> 6;        // wave's d-chunk: [512c, 512c+512)
        const int h = t & 63;
        const float* w1c = W1 + (size_t)(512 + c * 512) * 64 + h;  // coalesced over h
        float acc[4] = {0.f, 0.f, 0.f, 0.f};

        float wreg[2][16];
#pragma unroll
        for (int u = 0; u < 16; u++) wreg[0][u] = w1c[(size_t)u * 64];

#pragma unroll 2
        for (int dd = 0; dd < 512; dd += 16) {
            const int cur = (dd >> 4) & 1;       // static under unroll-2
            if (dd + 16 < 512) {
#pragma unroll
                for (int u = 0; u < 16; u++)
                    wreg[cur ^ 1][u] = w1c[(size_t)(dd + 16 + u) * 64];
            }
#pragma unroll
            for (int u4 = 0; u4 < 4; u4++) {
                // q via ds_read_b128 broadcast: 4 d-values per read per batch
                float4 qv[4];
#pragma unroll
                for (int j = 0; j < 4; j++)
                    qv[j] = *(const float4*)&sq[j][c * 512 + dd + u4 * 4];
#pragma unroll
                for (int uu = 0; uu < 4; uu++) {
                    const float wv = wreg[cur][u4 * 4 + uu];
                    acc[0] += (&qv[0].x)[uu] * wv;
                    acc[1] += (&qv[1].x)[uu] * wv;
                    acc[2] += (&qv[2].x)[uu] * wv;
                    acc[3] += (&qv[3].x)[uu] * wv;
                }
            }
        }
#pragma unroll
        for (int j = 0; j < 4; j++) red[c][j][h] = acc[j];
        __syncthreads();
        const int j2 = t >> 6;
        proj[(size_t)(b0 + j2) * 64 + h] =
            red[0][j2][h] + red[1][j2][h] + red[2][j2][h] + red[3][j2][h];
    }
}

// ---------------- attn: one 512-thread block per batch ----------------
__global__ __launch_bounds__(512) void attn_kernel(
    const float* __restrict__ keys, const float* __restrict__ frame,
    const int* __restrict__ mask, const float* __restrict__ W2,
    const bf16* __restrict__ w1kt, const float* __restrict__ proj,
    float* __restrict__ out)
{
    extern __shared__ char smem[];
    bf16* sk      = (bf16*)smem;                  // [128][520] bf16
    float* scores = (float*)(smem + SK_BYTES);    // [128]
    float* wts    = scores + 128;                 // [128]

    const int b = blockIdx.x;
    const int t = threadIdx.x;
    const int w = t >> 6;          // wave id 0..7
    const int lane = t & 63;
    const int m = lane & 15;
    const int q = lane >> 4;
    const int p0 = w * 16;         // this wave's 16 key rows

    // per-lane fold constants (L2-hot, issued early, consumed after kk loop)
    float pv[4], wv[4];
#pragma unroll
    for (int nt = 0; nt < 4; nt++) {
        pv[nt] = proj[b * 64 + nt * 16 + m];
        wv[nt] = W2[nt * 16 + m];
    }

    // ---- scores: C[p][h] = relu(keys@W1k + proj) @ W2, A direct-from-global ----
    const float* arow = keys + (size_t)b * (NP * NK) + (size_t)(p0 + m) * NK + q * 8;
    const bf16* bb = w1kt + m * 512 + q * 8;                  // + nt*8192 + kk*32
    bf16* swr = sk + (size_t)(p0 + m) * SKLD + q * 8;         // LDS stage for context

    f32x4 acc[4];
#pragma unroll
    for (int nt = 0; nt < 4; nt++) acc[nt] = (f32x4){0.f, 0.f, 0.f, 0.f};

    float4 Aa[2], Ab[2];
    bf16x8 Bp[2][4];
    Aa[0] = *(const float4*)(arow);
    Ab[0] = *(const float4*)(arow + 4);
#pragma unroll
    for (int nt = 0; nt < 4; nt++) Bp[0][nt] = *(const bf16x8*)(bb + nt * 8192);

#pragma unroll
    for (int kk = 0; kk < 16; kk++) {
        const int cur = kk & 1;
        if (kk < 15) {
            Aa[cur ^ 1] = *(const float4*)(arow + (kk + 1) * 32);
            Ab[cur ^ 1] = *(const float4*)(arow + (kk + 1) * 32 + 4);
#pragma unroll
            for (int nt = 0; nt < 4; nt++)
                Bp[cur ^ 1][nt] = *(const bf16x8*)(bb + nt * 8192 + (kk + 1) * 32);
        }
        bf16x8 Af;
        Af[0] = (bf16)Aa[cur].x; Af[1] = (bf16)Aa[cur].y;
        Af[2] = (bf16)Aa[cur].z; Af[3] = (bf16)Aa[cur].w;
        Af[4] = (bf16)Ab[cur].x; Af[5] = (bf16)Ab[cur].y;
        Af[6] = (bf16)Ab[cur].z; Af[7] = (bf16)Ab[cur].w;
        *(bf16x8*)(swr + kk * 32) = Af;     // stage bf16 keys for context phase
#pragma unroll
        for (int nt = 0; nt < 4; nt++)
            acc[nt] = __builtin_amdgcn_mfma_f32_16x16x32_bf16(Af, Bp[cur][nt], acc[nt], 0, 0, 0);
    }

    // fold 64 h-columns: relu(+proj) * w2, then reduce over the 16 h-lanes
    float pr[4] = {0.f, 0.f, 0.f, 0.f};
#pragma unroll
    for (int nt = 0; nt < 4; nt++)
#pragma unroll
        for (int r = 0; r < 4; r++)
            pr[r] += fmaxf(acc[nt][r] + pv[nt], 0.f) * wv[nt];

#pragma unroll
    for (int off = 1; off < 16; off <<= 1)
#pragma unroll
        for (int r = 0; r < 4; r++)
            pr[r] += __shfl_xor(pr[r], off);

    if (m == 0) {
#pragma unroll
        for (int r = 0; r < 4; r++) scores[p0 + q * 4 + r] = pr[r];
    }
    __syncthreads();

    // ---- masked softmax over 128 scores (wave 0), write weights ----
    if (t < 64) {
        const int pa = t, pb = t + 64;
        float s0 = (mask[b * 128 + pa] == 0) ? -INFINITY : scores[pa];
        float s1 = (mask[b * 128 + pb] == 0) ? -INFINITY : scores[pb];
        float mx = fmaxf(s0, s1);
#pragma unroll
        for (int off = 32; off; off >>= 1) mx = fmaxf(mx, __shfl_xor(mx, off));
        float e0 = __expf(s0 - mx), e1 = __expf(s1 - mx);
        float sum = e0 + e1;
#pragma unroll
        for (int off = 32; off; off >>= 1) sum += __shfl_xor(sum, off);
        const float inv = 1.0f / sum;
        e0 *= inv; e1 *= inv;
        wts[pa] = e0; wts[pb] = e1;
        float* wout = out + (size_t)NB * 1536;
        wout[b * 128 + pa] = e0;
        wout[b * 128 + pb] = e1;
    }
    __syncthreads();

    // ---- context[k] = sum_p w[p]*keys_bf16[p][k]; thread owns col t ----
    {
        float c0 = 0.f, c1 = 0.f;
#pragma unroll 8
        for (int p = 0; p < 128; p += 2) {
            const uint32_t u0 = (uint32_t)*(const uint16_t*)(sk + (size_t)p * SKLD + t);
            const uint32_t u1 = (uint32_t)*(const uint16_t*)(sk + (size_t)(p + 1) * SKLD + t);
            c0 += wts[p] * __uint_as_float(u0 << 16);
            c1 += wts[p + 1] * __uint_as_float(u1 << 16);
        }
        out[(size_t)b * 1536 + t] = c0 + c1;
    }
    // ---- frame passthrough: embeddings[:, 512:1536] = frameLSTM_h ----
    if (t < 256) {
        const float4 fv = *(const float4*)(frame + (size_t)b * 1024 + t * 4);
        *(float4*)(out + (size_t)b * 1536 + 512 + t * 4) = fv;
    }
}

extern "C" void kernel_launch(void* const* d_in, const int* in_sizes, int n_in,
                              void* d_out, int out_size, void* d_ws, size_t ws_size,
                              hipStream_t stream) {
    const float* query = (const float*)d_in[0];
    const float* keys  = (const float*)d_in[1];
    const float* frame = (const float*)d_in[2];
    const int*   mask  = (const int*)d_in[3];
    const float* W1    = (const float*)d_in[4];
    const float* W2    = (const float*)d_in[5];
    float* out = (float*)d_out;

    // ws: [0,64K) w1kt bf16 [64][512]; [64K,128K) proj fp32 [256][64]
    bf16* w1kt  = (bf16*)d_ws;
    float* proj = (float*)((char*)d_ws + (64 << 10));

    hipFuncSetAttribute((const void*)attn_kernel,
                        hipFuncAttributeMaxDynamicSharedMemorySize, SMEM_BYTES);

    prep_kernel<<<80, 256, 0, stream>>>(W1, query, frame, w1kt, proj);
    attn_kernel<<<256, 512, SMEM_BYTES, stream>>>(keys, frame, mask, W2,
                                                  w1kt, proj, out);
}